// Round 11
// baseline (597.840 us; speedup 1.0000x reference)
//
#include <hip/hip_runtime.h>
#include <cstdint>
#include <cstddef>

#define NTOT 4096
#define DIM  1024
#define NNEG 6
#define KTOP 2048
#define BK   64

using u32 = unsigned int;
using u64 = unsigned long long;

typedef __attribute__((ext_vector_type(8))) short bf16x8;
typedef __attribute__((ext_vector_type(16))) float f32x16;

// monotonic float->uint transform (total order, handles negatives)
__device__ __forceinline__ u32 monoU(float f){
  u32 b = __float_as_uint(f);
  return (b & 0x80000000u) ? ~b : (b | 0x80000000u);
}

// fp32 -> bf16 round-to-nearest-even (finite inputs)
__device__ __forceinline__ short f2bf(float f){
  u32 x = __float_as_uint(f);
  u32 r = x + 0x7FFFu + ((x >> 16) & 1u);
  return (short)(r >> 16);
}

// async 16B global->LDS (dest = wave-uniform base + lane*16)
__device__ __forceinline__ void gload16(const short* g, short* l){
  __builtin_amdgcn_global_load_lds(
      (const __attribute__((address_space(1))) void*)(g),
      (__attribute__((address_space(3))) void*)(l), 16, 0, 0);
}

// block-wide sum (blockDim.x == 256), result valid on ALL threads
__device__ __forceinline__ float blockSumAll(float v){
  __shared__ float lds[4];
  for (int o = 32; o; o >>= 1) v += __shfl_down(v, o);
  if ((threadIdx.x & 63) == 0) lds[threadIdx.x >> 6] = v;
  __syncthreads();
  float r = lds[0] + lds[1] + lds[2] + lds[3];
  __syncthreads();
  return r;
}

// ---------------- init ----------------
__global__ void initK(u64* __restrict__ nidxp, u64* __restrict__ best1p,
                      double* __restrict__ lossAcc){
  int i = blockIdx.x * 256 + threadIdx.x;
  if (i < NNEG * NTOT) nidxp[i] = ~0ULL;
  if (i < NTOT) best1p[i] = ~0ULL;
  if (i == 0) *lossAcc = 0.0;
}

// ---------------- per-row normalize stats + bf16 pack (wave per row) ----------------
__global__ __launch_bounds__(256) void rowNormPackK(const float* __restrict__ sf,
    float* __restrict__ norms, float* __restrict__ sumn, short* __restrict__ packbf){
  const int wv = threadIdx.x >> 6, lane = threadIdx.x & 63;
  const int row = blockIdx.x * 4 + wv;                 // 0 .. 8*4096-1
  const float4* x = reinterpret_cast<const float4*>(sf + (size_t)row * DIM);
  float4 v[4];
  float s = 0.0f;
  #pragma unroll
  for (int i = 0; i < 4; ++i){
    v[i] = x[lane + 64*i];
    s += v[i].x*v[i].x + v[i].y*v[i].y + v[i].z*v[i].z + v[i].w*v[i].w;
  }
  #pragma unroll
  for (int o = 1; o <= 32; o <<= 1) s += __shfl_xor(s, o);
  float t = fmaxf(sqrtf(s), 1e-12f);
  float inv = 1.0f / t;
  float s2 = 0.0f;
  short4* pb = reinterpret_cast<short4*>(packbf + (size_t)row * DIM);
  #pragma unroll
  for (int i = 0; i < 4; ++i){
    float a0 = v[i].x*inv, a1 = v[i].y*inv, a2 = v[i].z*inv, a3 = v[i].w*inv;
    s2 += a0*a0 + a1*a1 + a2*a2 + a3*a3;
    short4 pk; pk.x = f2bf(a0); pk.y = f2bf(a1); pk.z = f2bf(a2); pk.w = f2bf(a3);
    pb[lane + 64*i] = pk;
  }
  #pragma unroll
  for (int o = 1; o <= 32; o <<= 1) s2 += __shfl_xor(s2, o);
  if (lane == 0){ norms[row] = t; sumn[row] = s2; }
}

// ---------------- exact top-k mask (k = N/2), parallel radix select ----------------
__global__ __launch_bounds__(1024) void topkMaskK(const float* __restrict__ att,
                                                  float* __restrict__ mask){
  __shared__ u32 hist[256];
  __shared__ u32 Csuf[257];
  __shared__ u32 wsum[16];
  __shared__ u32 sprefix, sremain;
  const int tid = threadIdx.x, lane = tid & 63, wv = tid >> 6;
  u32 u[4];
  #pragma unroll
  for (int e = 0; e < 4; ++e) u[e] = monoU(att[tid*4 + e]);
  if (tid == 0){ sprefix = 0u; sremain = KTOP; }
  for (int shift = 24; shift >= 0; shift -= 8){
    __syncthreads();                       // prev round's sprefix/sremain visible
    u32 pfx = sprefix, rem = sremain;
    if (tid < 256) hist[tid] = 0u;
    __syncthreads();
    #pragma unroll
    for (int e = 0; e < 4; ++e){
      bool cand = (shift == 24) || ((u[e] >> (shift + 8)) == (pfx >> (shift + 8)));
      if (cand) atomicAdd(&hist[(u[e] >> shift) & 255u], 1u);
    }
    __syncthreads();
    u32 p = 0;
    if (tid < 256){
      p = hist[255 - tid];                 // reversed -> prefix = suffix of hist
      #pragma unroll
      for (int o = 1; o <= 32; o <<= 1){
        u32 t = __shfl_up(p, o);
        if (lane >= o) p += t;
      }
      if (lane == 63) wsum[wv] = p;
    }
    __syncthreads();
    if (tid < 256){
      u32 base = 0;
      for (int w = 0; w < wv; ++w) base += wsum[w];
      Csuf[255 - tid] = base + p;
      if (tid == 0) Csuf[256] = 0u;
    }
    __syncthreads();
    if (tid < 256){
      u32 Cb = Csuf[tid], Cb1 = Csuf[tid + 1];
      if (Cb >= rem && Cb1 < rem){
        sprefix = pfx | ((u32)tid << shift);
        sremain = rem - Cb1;
      }
    }
  }
  __syncthreads();
  u32 T = sprefix, need = sremain;
  u32 c = 0;
  #pragma unroll
  for (int e = 0; e < 4; ++e) c += (u[e] == T);
  u32 p = c;
  #pragma unroll
  for (int o = 1; o <= 32; o <<= 1){
    u32 t = __shfl_up(p, o);
    if (lane >= o) p += t;
  }
  if (lane == 63) wsum[wv] = p;
  __syncthreads();
  u32 base = 0;
  for (int w = 0; w < wv; ++w) base += wsum[w];
  u32 excl = base + p - c;
  #pragma unroll
  for (int e = 0; e < 4; ++e){
    bool m;
    if (u[e] > T) m = true;
    else if (u[e] == T){ m = (excl < need); excl++; }
    else m = false;
    mask[tid*4 + e] = m ? 1.0f : 0.0f;
  }
}

// ---------------- bf16 MFMA distance kernel (128x128 tile, BK=64, 32x32x16) ----------------
// A = frame0 rows (GATHER: gathered via best2 = anchors), B = frame fB rows.
// Row argmin key = sumn_B[j] - 2*dot (row-const dropped).
// GATHER=false additionally emits per-block column top-2 chunks.
template<bool GATHER>
__global__ __launch_bounds__(256) void distMfmaK(
    const short* __restrict__ packbf, const float* __restrict__ sumn,
    const int* __restrict__ best2, u64* __restrict__ rowMinP,
    float* __restrict__ cm1, int* __restrict__ cr1, float* __restrict__ cm2)
{
  __shared__ __align__(16) short As[128*BK];
  __shared__ __align__(16) short Bs[128*BK];
  const int bi = blockIdx.y, bj = blockIdx.x;
  const int fB = GATHER ? (2 + blockIdx.z) : 1;
  const short* Abf = packbf;                                  // frame 0 (q)
  const short* Bbf = packbf + (size_t)fB * NTOT * DIM;
  const float* sumB = sumn + fB * NTOT;
  u64* rmp = GATHER ? (rowMinP + (size_t)blockIdx.z * NTOT) : rowMinP;

  const int tid = threadIdx.x;
  const int lane = tid & 63, wv = tid >> 6;
  const int wr = wv >> 1, wc = wv & 1;

  // --- staging: per wave 32 rows of A and B; 4 instrs each (8 rows/instr) ---
  // LDS linear (row, slot): holds global k-chunk slot ^ (row&7); row&7 == lane>>3
  const short* aS[4]; const short* bS[4]; short* aD[4]; short* bD[4];
  #pragma unroll
  for (int s = 0; s < 4; ++s){
    const int r = wv*32 + s*8 + (lane >> 3);
    const int chunk = (lane & 7) ^ (lane >> 3);
    const int garow = bi*128 + r;
    const int arow = GATHER ? best2[garow] : garow;
    aS[s] = Abf + (size_t)arow * DIM + chunk*8;
    bS[s] = Bbf + (size_t)(bj*128 + r) * DIM + chunk*8;
    aD[s] = As + (wv*32 + s*8) * BK;
    bD[s] = Bs + (wv*32 + s*8) * BK;
  }

  // --- compute-side fragment addressing (swizzled ds_read_b128) ---
  const int lane31 = lane & 31, kh = lane >> 5, l7 = lane & 7;
  int offA[2][4], offB[2][4];
  #pragma unroll
  for (int m = 0; m < 2; ++m)
    #pragma unroll
    for (int ks = 0; ks < 4; ++ks){
      const int sl = ((ks*2 + kh) ^ l7) << 3;
      offA[m][ks] = (wr*64 + m*32 + lane31)*BK + sl;
      offB[m][ks] = (wc*64 + m*32 + lane31)*BK + sl;
    }

  f32x16 acc[2][2] = {};

  for (int k0 = 0; k0 < DIM; k0 += BK){
    #pragma unroll
    for (int s = 0; s < 4; ++s) gload16(aS[s] + k0, aD[s]);
    #pragma unroll
    for (int s = 0; s < 4; ++s) gload16(bS[s] + k0, bD[s]);
    __syncthreads();
    bf16x8 af[2][4], bfv[2][4];
    #pragma unroll
    for (int m = 0; m < 2; ++m)
      #pragma unroll
      for (int ks = 0; ks < 4; ++ks){
        af[m][ks]  = *(const bf16x8*)(As + offA[m][ks]);
        bfv[m][ks] = *(const bf16x8*)(Bs + offB[m][ks]);
      }
    #pragma unroll
    for (int ks = 0; ks < 4; ++ks)
      #pragma unroll
      for (int m = 0; m < 2; ++m)
        #pragma unroll
        for (int n = 0; n < 2; ++n)
          acc[m][n] = __builtin_amdgcn_mfma_f32_32x32x16_bf16(
              af[m][ks], bfv[n][ks], acc[m][n], 0, 0, 0);
    __syncthreads();
  }

  // --- epilogue 1: fused row-argmin ---
  // C frag (m,n) reg r: row = wr*64+m*32+(r&3)+8*(r>>2)+4*kh, col = wc*64+n*32+lane31
  const int c0 = bj*128 + wc*64 + lane31;
  const float sb0 = sumB[c0];
  const float sb1 = sumB[c0 + 32];
  #pragma unroll
  for (int m = 0; m < 2; ++m){
    #pragma unroll
    for (int reg = 0; reg < 16; ++reg){
      const int rloc = (reg & 3) + 8*(reg >> 2) + 4*kh;
      const int grow = bi*128 + wr*64 + m*32 + rloc;
      float k0v = sb0 - 2.0f * acc[m][0][reg];
      float k1v = sb1 - 2.0f * acc[m][1][reg];
      u64 pk  = ((u64)monoU(k0v) << 32) | (u32)c0;
      u64 pk1 = ((u64)monoU(k1v) << 32) | (u32)(c0 + 32);
      if (pk1 < pk) pk = pk1;
      #pragma unroll
      for (int off = 1; off <= 16; off <<= 1){
        u64 o = __shfl_xor(pk, off);
        if (o < pk) pk = o;
      }
      if (lane31 == 0) atomicMin(&rmp[grow], pk);
    }
  }

  // --- epilogue 2 (pair only): per-block column top-2 chunk ---
  if constexpr (!GATHER){
    const int gibase = bi*128 + wr*64;
    float M1[2], M2[2]; int R1[2];
    #pragma unroll
    for (int n = 0; n < 2; ++n){
      float m1 = INFINITY, m2 = INFINITY; int r1 = 0;
      #pragma unroll
      for (int m = 0; m < 2; ++m)
        #pragma unroll
        for (int reg = 0; reg < 16; ++reg){           // ascending rows per lane
          const int rloc = (reg & 3) + 8*(reg >> 2) + 4*kh;
          const int grow = gibase + m*32 + rloc;
          float v = sumn[grow] - 2.0f * acc[m][n][reg];  // col-const dropped
          if (v < m1){ m2 = m1; m1 = v; r1 = grow; }
          else m2 = fminf(m2, v);
        }
      // merge with partner lane (kh^1): same col, other row set
      float o1 = __shfl_xor(m1, 32), o2 = __shfl_xor(m2, 32);
      int   oR = __shfl_xor(r1, 32);
      if (o1 < m1 || (o1 == m1 && oR < r1)){
        m2 = fminf(m2, m1); m1 = o1; r1 = oR; m2 = fminf(m2, o2);
      } else m2 = fminf(m2, o1);
      M1[n] = m1; M2[n] = m2; R1[n] = r1;
    }
    __syncthreads();
    float* Lm1 = reinterpret_cast<float*>(As);        // [128][2] contribs
    int*   Lr1 = reinterpret_cast<int*>(As) + 256;
    float* Lm2 = reinterpret_cast<float*>(As) + 512;
    if (kh == 0){
      #pragma unroll
      for (int n = 0; n < 2; ++n){
        const int c = wc*64 + n*32 + lane31;
        Lm1[c*2 + wr] = M1[n];
        Lr1[c*2 + wr] = R1[n];
        Lm2[c*2 + wr] = M2[n];
      }
    }
    __syncthreads();
    if (tid < 128){
      float A1 = Lm1[tid*2],   A2 = Lm2[tid*2];   int Ar = Lr1[tid*2];
      float B1 = Lm1[tid*2+1], B2 = Lm2[tid*2+1]; int Br = Lr1[tid*2+1];
      float M1f, M2f; int R1f;
      if (B1 < A1 || (B1 == A1 && Br < Ar)){ M1f = B1; R1f = Br; M2f = fminf(B2, A1); }
      else                                 { M1f = A1; R1f = Ar; M2f = fminf(A2, B1); }
      const int gc = bj*128 + tid;
      cm1[(size_t)bi*NTOT + gc] = M1f;
      cr1[(size_t)bi*NTOT + gc] = R1f;
      cm2[(size_t)bi*NTOT + gc] = M2f;
    }
  }
}

// ---------------- column chunk merge + ratio test ----------------
__global__ __launch_bounds__(256) void colMergeK(const float* __restrict__ cm1,
    const int* __restrict__ cr1, const float* __restrict__ cm2,
    const float* __restrict__ sumnP, int* __restrict__ best2, int* __restrict__ ratioOk){
  int j = blockIdx.x * 256 + threadIdx.x;
  float M1 = cm1[j]; int R1 = cr1[j]; float M2 = cm2[j];
  for (int c = 1; c < 32; ++c){
    size_t o = (size_t)c * NTOT + j;
    float v1 = cm1[o]; int rr = cr1[o]; float v2 = cm2[o];
    if (v1 < M1 || (v1 == M1 && rr < R1)){
      M2 = fminf(M2, M1); M1 = v1; R1 = rr; M2 = fminf(M2, v2);
    } else M2 = fminf(M2, v1);
  }
  best2[j] = R1;
  float sbj = sumnP[j];
  float d1 = sqrtf(fmaxf(M1 + sbj, 0.0f));
  float ds = sqrtf(fmaxf(M2 + sbj, 0.0f));
  ratioOk[j] = (d1 / ds <= 0.9f) ? 1 : 0;   // NaN -> false, matches ref
}

// ---------------- fused tail: valid gate + dpos + dneg + hinge ----------------
// exact algebra: invalid j contributes 0 -> skip all work for it
__global__ __launch_bounds__(256) void tailK(const float* __restrict__ sf,
    const float* __restrict__ norms, const u64* __restrict__ best1p,
    const int* __restrict__ best2, const int* __restrict__ ratioOk,
    const float* __restrict__ attm, const u64* __restrict__ nidxp,
    double* __restrict__ lossAcc){
  const int j = blockIdx.x;
  const int b2 = best2[j];
  bool ok = ((int)(best1p[b2] & 0xFFFFFFFFu) == j) && (ratioOk[j] != 0) && (attm[j] > 0.0f);
  if (!ok) return;
  const float ta = norms[b2];
  float4 av = reinterpret_cast<const float4*>(sf + (size_t)b2 * DIM)[threadIdx.x];
  const float a0 = av.x/ta, a1 = av.y/ta, a2 = av.z/ta, a3 = av.w/ta;
  const float tp = norms[NTOT + j];
  float4 pv = reinterpret_cast<const float4*>(sf + (size_t)(NTOT + j) * DIM)[threadIdx.x];
  float d0 = a0 - pv.x/tp, d1 = a1 - pv.y/tp, d2 = a2 - pv.z/tp, d3 = a3 - pv.w/tp;
  float dpos = blockSumAll(d0*d0 + d1*d1 + d2*d2 + d3*d3);
  float lsum = 0.0f;
  for (int t = 0; t < NNEG; ++t){
    int nidx = (int)(nidxp[(size_t)t * NTOT + j] & 0xFFFFFFFFu);
    int nrow = (2 + t) * NTOT + nidx;
    float tn = norms[nrow];
    float4 nv = reinterpret_cast<const float4*>(sf + (size_t)nrow * DIM)[threadIdx.x];
    float e0 = a0 - nv.x/tn, e1 = a1 - nv.y/tn, e2 = a2 - nv.z/tn, e3 = a3 - nv.w/tn;
    float dn = blockSumAll(e0*e0 + e1*e1 + e2*e2 + e3*e3);
    lsum += fmaxf(dpos - dn + 1.1f, 0.0f);
  }
  if (threadIdx.x == 0 && lsum > 0.0f) atomicAdd(lossAcc, (double)lsum);
}

__global__ void finK(const double* __restrict__ lossAcc, float* __restrict__ out){
  out[0] = (float)(*lossAcc);   // WEIGHT = 1.0
}

// ---------------- launcher ----------------
extern "C" void kernel_launch(void* const* d_in, const int* in_sizes, int n_in,
                              void* d_out, int out_size, void* d_ws, size_t ws_size,
                              hipStream_t stream){
  const float* sf  = (const float*)d_in[0];   // [8,4096,1024] f32
  const float* att = (const float*)d_in[1];   // [8,4096] f32
  char* w = (char*)d_ws;
  size_t off = 0;
  auto alloc = [&](size_t bytes)->void*{
    off = (off + 255) & ~(size_t)255;
    void* p = w + off; off += bytes; return p;
  };
  short* packbf = (short*)alloc((size_t)8 * NTOT * DIM * 2);   // 64 MB bf16 normalized
  float* norms  = (float*)alloc((size_t)8 * NTOT * 4);
  float* sumn   = (float*)alloc((size_t)8 * NTOT * 4);
  float* attm   = (float*)alloc((size_t)NTOT * 4);
  u64*   best1p = (u64*)  alloc((size_t)NTOT * 8);
  int*   best2  = (int*)  alloc((size_t)NTOT * 4);
  int*   ratOk  = (int*)  alloc((size_t)NTOT * 4);
  u64*   nidxp  = (u64*)  alloc((size_t)NNEG * NTOT * 8);
  float* cm1    = (float*)alloc((size_t)32 * NTOT * 4);
  int*   cr1    = (int*)  alloc((size_t)32 * NTOT * 4);
  float* cm2    = (float*)alloc((size_t)32 * NTOT * 4);
  double* lossAcc = (double*)alloc(8);

  initK<<<dim3(96), dim3(256), 0, stream>>>(nidxp, best1p, lossAcc);
  rowNormPackK<<<dim3(8192), dim3(256), 0, stream>>>(sf, norms, sumn, packbf);
  topkMaskK<<<dim3(1), dim3(1024), 0, stream>>>(att + NTOT, attm);
  distMfmaK<false><<<dim3(32,32,1), dim3(256), 0, stream>>>(
      packbf, sumn, nullptr, best1p, cm1, cr1, cm2);
  colMergeK<<<dim3(16), dim3(256), 0, stream>>>(cm1, cr1, cm2, sumn + NTOT, best2, ratOk);
  distMfmaK<true><<<dim3(32,32,NNEG), dim3(256), 0, stream>>>(
      packbf, sumn, best2, nidxp, nullptr, nullptr, nullptr);
  tailK<<<dim3(NTOT), dim3(256), 0, stream>>>(sf, norms, best1p, best2, ratOk, attm, nidxp, lossAcc);
  finK<<<dim3(1), dim3(1), 0, stream>>>(lossAcc, (float*)d_out);
}